// Round 4
// baseline (181.714 us; speedup 1.0000x reference)
//
#include <hip/hip_runtime.h>
#include <math.h>

// ---------------- problem constants ----------------
#define BB   16      // batch
#define TT   50      // targets per image
#define NCLS 80
#define IMGF 608.0f

#define H0 76
#define H1 38
#define H2 19
#define N0 277248   // 16*3*76*76
#define N1 69312    // 16*3*38*38
#define N2 17328    // 16*3*19*19

// float4 counts per scale (N*85/4 — all divisible by 4)
#define C0 5891520
#define C1 1472880
#define C2 368220

// pos: one WAVE per (scale, order). 200 blocks/scale * 4 waves = 800 orders.
#define POS_BLOCKS_PER_SCALE 200
#define NPOS_BLOCKS (3*POS_BLOCKS_PER_SCALE)   // 600

// noobj (R9): dedicated max-occupancy stream kernel.
// R3 post-mortem: fused k_main stuck at ~55us with VALU fix neutral ->
// noobj stream and pos gathers were entangled (congestion + shared
// counters). Split: stream gets 2015 blocks (7.9 waves/SIMD vs 4) and
// 15 f4/thread; pos runs after on a quiet memory system.
#define F4_PER_THREAD 15
#define F4_PER_BLOCK (256*F4_PER_THREAD)       // 3840
#define NOB0 1535  // ceil(C0/3840)
#define NOB1 384   // ceil(C1/3840)
#define NOB2 96    // ceil(C2/3840)
#define NOBT (NOB0+NOB1+NOB2)                  // 2015

__constant__ float c_anchors[3][3][2] = {
    {{12.f,16.f},{19.f,36.f},{40.f,28.f}},
    {{36.f,75.f},{76.f,55.f},{72.f,146.f}},
    {{142.f,110.f},{192.f,243.f},{459.f,401.f}}};
__constant__ int c_H[3] = {H0, H1, H2};

__device__ __forceinline__ float sigmoidf_(float x) { return 1.0f / (1.0f + expf(-x)); }
__device__ __forceinline__ float clipf_(float x, float lo, float hi) {
    return fminf(fmaxf(x, lo), hi);
}

__device__ __forceinline__ float iou4(float ax, float ay, float aw, float ah,
                                      float bx, float by, float bw, float bh) {
    float ax1 = ax - aw * 0.5f, ay1 = ay - ah * 0.5f;
    float ax2 = ax + aw * 0.5f, ay2 = ay + ah * 0.5f;
    float bx1 = bx - bw * 0.5f, by1 = by - bh * 0.5f;
    float bx2 = bx + bw * 0.5f, by2 = by + bh * 0.5f;
    float iw = fmaxf(fminf(ax2, bx2) - fmaxf(ax1, bx1), 0.f);
    float ih = fmaxf(fminf(ay2, by2) - fmaxf(ay1, by1), 0.f);
    float inter = iw * ih;
    float uni = (ax2 - ax1) * (ay2 - ay1) + (bx2 - bx1) * (by2 - by1) - inter + 1e-7f;
    return inter / uni;
}

// anchor match + cell for one (scale, target row). returns -1 if invalid target
__device__ __forceinline__ int target_cell(const float* tr, int s, float& cx, float& cy,
                                           float& w, float& h, int& best, int& gxi, int& gyi) {
    float t4 = tr[4];
    if (!(t4 > 0.f)) return -1;
    cx = clipf_(tr[0], 0.f, 1.f);
    cy = clipf_(tr[1], 0.f, 1.f);
    w  = clipf_(tr[2], 0.f, 1.f);
    h  = clipf_(tr[3], 0.f, 1.f);
    best = 0;
    float bi = -1e30f;
    #pragma unroll
    for (int a = 0; a < 3; a++) {
        float aw = c_anchors[s][a][0] / IMGF;
        float ah = c_anchors[s][a][1] / IMGF;
        float v = iou4(0.5f, 0.5f, aw, ah, cx, cy, w, h);
        if (v > bi) { bi = v; best = a; }  // first-max == jnp.argmax
    }
    int H = c_H[s];
    gxi = (int)(cx * (float)H); gxi = min(max(gxi, 0), H - 1);
    gyi = (int)(cy * (float)H); gyi = min(max(gyi, 0), H - 1);
    return 0;
}

// ---- kernel A: no-object BCE, pure coalesced float4 stream ----
__global__ __launch_bounds__(256, 8) void k_noobj(const float* __restrict__ p0,
                                                  const float* __restrict__ p1,
                                                  const float* __restrict__ p2,
                                                  float* __restrict__ noobj_part) { // [NOBT]
    int blk = blockIdx.x;
    int lane = threadIdx.x & 63;
    int wv = threadIdx.x >> 6;

    const float4* pv; unsigned cnt; int rb;
    if (blk < NOB0)             { pv = (const float4*)p0; cnt = C0; rb = blk; }
    else if (blk < NOB0 + NOB1) { pv = (const float4*)p1; cnt = C1; rb = blk - NOB0; }
    else                        { pv = (const float4*)p2; cnt = C2; rb = blk - NOB0 - NOB1; }
    unsigned gbase = (unsigned)rb * F4_PER_BLOCK + threadIdx.x;

    float s = 0.f;
    #pragma unroll 1
    for (int c = 0; c < 3; c++) {               // 3 chunks x 5 float4s = 15
        float4 v[5];
        #pragma unroll
        for (int j = 0; j < 5; j++) {           // 5 loads in flight (MLP)
            unsigned q = gbase + (c * 5 + j) * 256;
            v[j] = (q < cnt) ? pv[q] : make_float4(0.f, 0.f, 0.f, 0.f);
        }
        #pragma unroll
        for (int j = 0; j < 5; j++) {
            unsigned q = gbase + (c * 5 + j) * 256;
            if (q < cnt) {
                unsigned m = (4u * q) % 85u;    // float idx of v[j].x mod 85
                if (m - 1u <= 3u) {             // m in [1,4] -> contains a ch4
                    float4 vv = v[j];
                    float x = (m == 4u) ? vv.x : (m == 3u) ? vv.y
                            : (m == 2u) ? vv.z : vv.w;
                    // -log1p(-clip(sigmoid(x),1e-10,1-1e-10)) == min(softplus(x), -ln(1e-10))
                    float sp = fmaxf(x, 0.f) + __logf(1.f + __expf(-fabsf(x)));
                    s += fminf(sp, 23.02585093f);
                }
            }
        }
    }
    #pragma unroll
    for (int off = 32; off > 0; off >>= 1) s += __shfl_xor(s, off, 64);
    __shared__ float sm1[4];
    if (lane == 0) sm1[wv] = s;
    __syncthreads();
    if (threadIdx.x == 0)
        noobj_part[blk] = sm1[0] + sm1[1] + sm1[2] + sm1[3];
}

// ---- kernel B: positive cells, one WAVE per (scale, order) ----
__global__ __launch_bounds__(256) void k_pos(const float* __restrict__ p0,
                                             const float* __restrict__ p1,
                                             const float* __restrict__ p2,
                                             const float* __restrict__ targets,
                                             float* __restrict__ pos_part) {   // [NPOS_BLOCKS*5]
    int bp = blockIdx.x;
    int lane = threadIdx.x & 63;
    int wv = threadIdx.x >> 6;

    int s = bp / POS_BLOCKS_PER_SCALE;
    int order = (bp % POS_BLOCKS_PER_SCALE) * 4 + wv;   // < 800

    float v_coord = 0.f, v_obj = 0.f, v_noadj = 0.f, v_cls = 0.f, v_np = 0.f;

    int b = order / TT, t = order % TT;
    const float* tr = targets + order * 85;
    float cx, cy, w, h; int best, gxi, gyi;
    if (target_cell(tr, s, cx, cy, w, h, best, gxi, gyi) == 0) {  // wave-uniform
        int H = c_H[s];
        int flat = ((b * 3 + best) * H + gyi) * H + gxi;

        // inline last-write-wins: any LATER valid target in this image on same cell?
        bool lost = false;
        int tp = t + 1 + lane;
        if (tp < TT) {
            const float* tr2 = targets + (b * TT + tp) * 85;
            float cx2, cy2, w2, h2; int best2, gxi2, gyi2;
            if (target_cell(tr2, s, cx2, cy2, w2, h2, best2, gxi2, gyi2) == 0) {
                int flat2 = ((b * 3 + best2) * H + gyi2) * H + gxi2;
                lost = (flat2 == flat);
            }
        }
        if (__ballot(lost) == 0ull) {   // this order wins the cell
            const float* pred = (s == 0) ? p0 : (s == 1) ? p1 : p2;
            const float* pc = pred + (long long)flat * 85;

            float px = sigmoidf_(pc[0]);
            float py = sigmoidf_(pc[1]);
            float bx = clipf_((px + (float)gxi) / (float)H, 0.f, 1.f);
            float by = clipf_((py + (float)gyi) / (float)H, 0.f, 1.f);
            float aw = c_anchors[s][best][0], ah = c_anchors[s][best][1];
            float bwv = clipf_(expf(clipf_(pc[2], -10.f, 10.f)) * aw / IMGF, 0.f, 1.f);
            float bhv = clipf_(expf(clipf_(pc[3], -10.f, 10.f)) * ah / IMGF, 0.f, 1.f);
            float iou = iou4(bx, by, bwv, bhv, cx, cy, w, h);

            float p = clipf_(sigmoidf_(pc[4]), 1e-10f, 1.0f);

            // class BCE split across lanes: lane k -> class k (+ class k+64 if k<16)
            float pcv = clipf_(sigmoidf_(pc[5 + lane]), 1e-10f, 1.0f);
            float tc  = clipf_(tr[5 + lane], 0.f, 1.f);
            float cl  = -(tc * logf(pcv) + (1.f - tc) * log1pf(-pcv));
            if (lane < NCLS - 64) {
                float pcv2 = clipf_(sigmoidf_(pc[5 + 64 + lane]), 1e-10f, 1.0f);
                float tc2  = clipf_(tr[5 + 64 + lane], 0.f, 1.f);
                cl += -(tc2 * logf(pcv2) + (1.f - tc2) * log1pf(-pcv2));
            }
            #pragma unroll
            for (int off = 32; off > 0; off >>= 1) cl += __shfl_xor(cl, off, 64);

            v_coord = 1.f - iou;
            v_obj   = -logf(p);
            v_noadj = -log1pf(-p);
            v_cls   = cl;
            v_np    = 1.f;
        }
    }

    __shared__ float sm5[4][5];
    if (lane == 0) {
        sm5[wv][0] = v_coord; sm5[wv][1] = v_obj; sm5[wv][2] = v_noadj;
        sm5[wv][3] = v_cls;   sm5[wv][4] = v_np;
    }
    __syncthreads();
    if (threadIdx.x < 5) {
        pos_part[bp * 5 + threadIdx.x] =
            sm5[0][threadIdx.x] + sm5[1][threadIdx.x] +
            sm5[2][threadIdx.x] + sm5[3][threadIdx.x];
    }
}

// ---- kernel C: reduce partials + final combine ----
__global__ __launch_bounds__(256) void k_final(const float* __restrict__ noobj_part,
                                               const float* __restrict__ pos_part,
                                               float* __restrict__ out) {
    float n0 = 0.f, n1 = 0.f, n2 = 0.f;
    #pragma unroll
    for (int r = 0; r < 8; r++) {                  // covers 2048 >= 2015
        int i = threadIdx.x + r * 256;
        if (i < NOB0)                    n0 += noobj_part[i];
        else if (i < NOB0 + NOB1)        n1 += noobj_part[i];
        else if (i < NOBT)               n2 += noobj_part[i];
    }
    float ps[3][5] = {};
    for (int i = threadIdx.x; i < NPOS_BLOCKS; i += 256) {
        int s = i / POS_BLOCKS_PER_SCALE;
        #pragma unroll
        for (int q = 0; q < 5; q++) ps[s][q] += pos_part[i * 5 + q];
    }

    __shared__ float red[18][256];
    red[0][threadIdx.x] = n0;
    red[1][threadIdx.x] = n1;
    red[2][threadIdx.x] = n2;
    #pragma unroll
    for (int s = 0; s < 3; s++) {
        #pragma unroll
        for (int q = 0; q < 5; q++) red[3 + s * 5 + q][threadIdx.x] = ps[s][q];
    }
    __syncthreads();
    for (int off = 128; off > 0; off >>= 1) {
        if (threadIdx.x < off) {
            #pragma unroll
            for (int r = 0; r < 18; r++)
                red[r][threadIdx.x] += red[r][threadIdx.x + off];
        }
        __syncthreads();
    }
    if (threadIdx.x == 0) {
        const float ncell[3] = {(float)N0, (float)N1, (float)N2};
        float coord = 0.f, conf = 0.f, cls = 0.f;
        #pragma unroll
        for (int s = 0; s < 3; s++) {
            float noobjTot = red[s][0];
            float co    = red[3 + s * 5 + 0][0];
            float ob    = red[3 + s * 5 + 1][0];
            float noadj = red[3 + s * 5 + 2][0];
            float cl    = red[3 + s * 5 + 3][0];
            float npos  = red[3 + s * 5 + 4][0];
            float nneg = ncell[s] - npos;
            float dn = fmaxf(npos, 1.f);
            conf += ob / dn + 0.5f * (noobjTot - noadj) / fmaxf(nneg, 1.f);
            if (npos > 0.f) {
                coord += co / dn;
                cls   += cl / fmaxf(npos * (float)NCLS, 1.f);
            }
        }
        out[0] = 5.0f * coord + conf + 1.0f * cls;
        out[1] = coord;
        out[2] = conf;
        out[3] = cls;
    }
}

extern "C" void kernel_launch(void* const* d_in, const int* in_sizes, int n_in,
                              void* d_out, int out_size, void* d_ws, size_t ws_size,
                              hipStream_t stream) {
    const float* p0 = (const float*)d_in[0];
    const float* p1 = (const float*)d_in[1];
    const float* p2 = (const float*)d_in[2];
    const float* tg = (const float*)d_in[3];
    float* out = (float*)d_out;

    char* ws = (char*)d_ws;
    float* noobj_part = (float*)ws;              // NOBT floats (8060 B)
    float* pos_part   = (float*)(ws + 16384);    // NPOS_BLOCKS*5 floats (12 KB)

    k_noobj<<<NOBT, 256, 0, stream>>>(p0, p1, p2, noobj_part);
    k_pos<<<NPOS_BLOCKS, 256, 0, stream>>>(p0, p1, p2, tg, pos_part);
    k_final<<<1, 256, 0, stream>>>(noobj_part, pos_part, out);
}

// Round 5
// 158.520 us; speedup vs baseline: 1.1463x; 1.1463x over previous
//
#include <hip/hip_runtime.h>
#include <math.h>

// ---------------- problem constants ----------------
#define BB   16      // batch
#define TT   50      // targets per image
#define NCLS 80
#define IMGF 608.0f

#define H0 76
#define H1 38
#define H2 19
#define N0 277248   // 16*3*76*76
#define N1 69312    // 16*3*38*38
#define N2 17328    // 16*3*19*19
#define NTOT (N0+N1+N2)   // 363888

// noobj (R10): back to the CH4 GATHER (R0 structure — empirically fastest:
// R0 kernels ~43us vs stream variants 59-65us; stream's 5x byte overhead
// never repaid). R0 ran the gather on 178 blocks = 178 CUs; the scattered
// gather is limited by per-CU L1 address-divergence processing (~0.5
// lines/cy/CU), so spread it over ALL CUs: 2 cells/thread -> 712 blocks,
// per-scale block ranges (wave-uniform pointer, no select chain).
#define NB0 542    // ceil(N0/512)
#define NB1 136    // ceil(N1/512)
#define NB2 34     // ceil(N2/512)
#define NOBT (NB0+NB1+NB2)                     // 712

// pos: one WAVE per (scale, order). 200 blocks/scale * 4 waves = 800 orders.
#define POS_BLOCKS_PER_SCALE 200
#define NPOS_BLOCKS (3*POS_BLOCKS_PER_SCALE)   // 600
#define NBLK (NOBT + NPOS_BLOCKS)              // 1312

__constant__ float c_anchors[3][3][2] = {
    {{12.f,16.f},{19.f,36.f},{40.f,28.f}},
    {{36.f,75.f},{76.f,55.f},{72.f,146.f}},
    {{142.f,110.f},{192.f,243.f},{459.f,401.f}}};
__constant__ int c_H[3] = {H0, H1, H2};

__device__ __forceinline__ float sigmoidf_(float x) { return 1.0f / (1.0f + expf(-x)); }
__device__ __forceinline__ float clipf_(float x, float lo, float hi) {
    return fminf(fmaxf(x, lo), hi);
}

__device__ __forceinline__ float iou4(float ax, float ay, float aw, float ah,
                                      float bx, float by, float bw, float bh) {
    float ax1 = ax - aw * 0.5f, ay1 = ay - ah * 0.5f;
    float ax2 = ax + aw * 0.5f, ay2 = ay + ah * 0.5f;
    float bx1 = bx - bw * 0.5f, by1 = by - bh * 0.5f;
    float bx2 = bx + bw * 0.5f, by2 = by + bh * 0.5f;
    float iw = fmaxf(fminf(ax2, bx2) - fmaxf(ax1, bx1), 0.f);
    float ih = fmaxf(fminf(ay2, by2) - fmaxf(ay1, by1), 0.f);
    float inter = iw * ih;
    float uni = (ax2 - ax1) * (ay2 - ay1) + (bx2 - bx1) * (by2 - by1) - inter + 1e-7f;
    return inter / uni;
}

// anchor match + cell for one (scale, target row). returns -1 if invalid target
__device__ __forceinline__ int target_cell(const float* tr, int s, float& cx, float& cy,
                                           float& w, float& h, int& best, int& gxi, int& gyi) {
    float t4 = tr[4];
    if (!(t4 > 0.f)) return -1;
    cx = clipf_(tr[0], 0.f, 1.f);
    cy = clipf_(tr[1], 0.f, 1.f);
    w  = clipf_(tr[2], 0.f, 1.f);
    h  = clipf_(tr[3], 0.f, 1.f);
    best = 0;
    float bi = -1e30f;
    #pragma unroll
    for (int a = 0; a < 3; a++) {
        float aw = c_anchors[s][a][0] / IMGF;
        float ah = c_anchors[s][a][1] / IMGF;
        float v = iou4(0.5f, 0.5f, aw, ah, cx, cy, w, h);
        if (v > bi) { bi = v; best = a; }  // first-max == jnp.argmax
    }
    int H = c_H[s];
    gxi = (int)(cx * (float)H); gxi = min(max(gxi, 0), H - 1);
    gyi = (int)(cy * (float)H); gyi = min(max(gyi, 0), H - 1);
    return 0;
}

// ---- main kernel: blocks [0,NOBT) = noobj ch4 gather (per-scale ranges,
//      2 cells/thread); blocks [NOBT,NBLK) = positive waves (R0-verbatim).
//      Two dispatches kept: grid-wide sync costs ~50us on 8 XCDs (R6). ----
__global__ __launch_bounds__(256) void k_main(const float* __restrict__ p0,
                                              const float* __restrict__ p1,
                                              const float* __restrict__ p2,
                                              const float* __restrict__ targets,
                                              float* __restrict__ noobj_part,   // [NOBT]
                                              float* __restrict__ pos_part) {   // [NPOS_BLOCKS*5]
    int blk = blockIdx.x;
    int lane = threadIdx.x & 63;
    int wv = threadIdx.x >> 6;

    __shared__ float sm1[4];
    __shared__ float sm5[4][5];

    if (blk < NOBT) {
        // ---------- no-object BCE: ch4 gather, one scale per block range ----------
        const float* pv; unsigned n; int rb;
        if (blk < NB0)            { pv = p0; n = N0; rb = blk; }
        else if (blk < NB0 + NB1) { pv = p1; n = N1; rb = blk - NB0; }
        else                      { pv = p2; n = N2; rb = blk - NB0 - NB1; }
        unsigned base = (unsigned)rb * 512u + threadIdx.x;

        unsigned g0 = base, g1 = base + 256u;
        // both loads issue before either use (independent regs)
        float x0 = (g0 < n) ? pv[g0 * 85u + 4u] : 0.f;
        float x1 = (g1 < n) ? pv[g1 * 85u + 4u] : 0.f;

        // -log1p(-clip(sigmoid(x),1e-10,1-1e-10)) == min(softplus(x), -ln(1e-10))
        float s = 0.f;
        if (g0 < n) {
            float sp = fmaxf(x0, 0.f) + __logf(1.f + __expf(-fabsf(x0)));
            s += fminf(sp, 23.02585093f);
        }
        if (g1 < n) {
            float sp = fmaxf(x1, 0.f) + __logf(1.f + __expf(-fabsf(x1)));
            s += fminf(sp, 23.02585093f);
        }
        #pragma unroll
        for (int off = 32; off > 0; off >>= 1) s += __shfl_xor(s, off, 64);
        if (lane == 0) sm1[wv] = s;
        __syncthreads();
        if (threadIdx.x == 0)
            noobj_part[blk] = sm1[0] + sm1[1] + sm1[2] + sm1[3];
    } else {
        // ---------- positive cells: one WAVE per (scale, order) ----------
        int bp = blk - NOBT;
        int s = bp / POS_BLOCKS_PER_SCALE;
        int order = (bp % POS_BLOCKS_PER_SCALE) * 4 + wv;   // < 800

        float v_coord = 0.f, v_obj = 0.f, v_noadj = 0.f, v_cls = 0.f, v_np = 0.f;

        int b = order / TT, t = order % TT;
        const float* tr = targets + order * 85;
        float cx, cy, w, h; int best, gxi, gyi;
        if (target_cell(tr, s, cx, cy, w, h, best, gxi, gyi) == 0) {  // wave-uniform
            int H = c_H[s];
            int flat = ((b * 3 + best) * H + gyi) * H + gxi;

            // inline last-write-wins: any LATER valid target in this image on same cell?
            bool lost = false;
            int tp = t + 1 + lane;
            if (tp < TT) {
                const float* tr2 = targets + (b * TT + tp) * 85;
                float cx2, cy2, w2, h2; int best2, gxi2, gyi2;
                if (target_cell(tr2, s, cx2, cy2, w2, h2, best2, gxi2, gyi2) == 0) {
                    int flat2 = ((b * 3 + best2) * H + gyi2) * H + gxi2;
                    lost = (flat2 == flat);
                }
            }
            if (__ballot(lost) == 0ull) {   // this order wins the cell
                const float* pred = (s == 0) ? p0 : (s == 1) ? p1 : p2;
                const float* pc = pred + (long long)flat * 85;

                float px = sigmoidf_(pc[0]);
                float py = sigmoidf_(pc[1]);
                float bx = clipf_((px + (float)gxi) / (float)H, 0.f, 1.f);
                float by = clipf_((py + (float)gyi) / (float)H, 0.f, 1.f);
                float aw = c_anchors[s][best][0], ah = c_anchors[s][best][1];
                float bwv = clipf_(expf(clipf_(pc[2], -10.f, 10.f)) * aw / IMGF, 0.f, 1.f);
                float bhv = clipf_(expf(clipf_(pc[3], -10.f, 10.f)) * ah / IMGF, 0.f, 1.f);
                float iou = iou4(bx, by, bwv, bhv, cx, cy, w, h);

                float p = clipf_(sigmoidf_(pc[4]), 1e-10f, 1.0f);

                // class BCE split across lanes: lane k -> class k (+ class k+64 if k<16)
                float pcv = clipf_(sigmoidf_(pc[5 + lane]), 1e-10f, 1.0f);
                float tc  = clipf_(tr[5 + lane], 0.f, 1.f);
                float cl  = -(tc * logf(pcv) + (1.f - tc) * log1pf(-pcv));
                if (lane < NCLS - 64) {
                    float pcv2 = clipf_(sigmoidf_(pc[5 + 64 + lane]), 1e-10f, 1.0f);
                    float tc2  = clipf_(tr[5 + 64 + lane], 0.f, 1.f);
                    cl += -(tc2 * logf(pcv2) + (1.f - tc2) * log1pf(-pcv2));
                }
                #pragma unroll
                for (int off = 32; off > 0; off >>= 1) cl += __shfl_xor(cl, off, 64);

                v_coord = 1.f - iou;
                v_obj   = -logf(p);
                v_noadj = -log1pf(-p);
                v_cls   = cl;
                v_np    = 1.f;
            }
        }

        if (lane == 0) {
            sm5[wv][0] = v_coord; sm5[wv][1] = v_obj; sm5[wv][2] = v_noadj;
            sm5[wv][3] = v_cls;   sm5[wv][4] = v_np;
        }
        __syncthreads();
        if (threadIdx.x < 5) {
            pos_part[bp * 5 + threadIdx.x] =
                sm5[0][threadIdx.x] + sm5[1][threadIdx.x] +
                sm5[2][threadIdx.x] + sm5[3][threadIdx.x];
        }
    }
}

// ---- kernel D: reduce partials + final combine ----
__global__ __launch_bounds__(256) void k_final(const float* __restrict__ noobj_part,
                                               const float* __restrict__ pos_part,
                                               float* __restrict__ out) {
    float n0 = 0.f, n1 = 0.f, n2 = 0.f;
    #pragma unroll
    for (int r = 0; r < 3; r++) {                  // covers 768 >= 712
        int i = threadIdx.x + r * 256;
        if (i < NB0)                 n0 += noobj_part[i];
        else if (i < NB0 + NB1)      n1 += noobj_part[i];
        else if (i < NOBT)           n2 += noobj_part[i];
    }
    float ps[3][5] = {};
    for (int i = threadIdx.x; i < NPOS_BLOCKS; i += 256) {
        int s = i / POS_BLOCKS_PER_SCALE;
        #pragma unroll
        for (int q = 0; q < 5; q++) ps[s][q] += pos_part[i * 5 + q];
    }

    __shared__ float red[18][256];
    red[0][threadIdx.x] = n0;
    red[1][threadIdx.x] = n1;
    red[2][threadIdx.x] = n2;
    #pragma unroll
    for (int s = 0; s < 3; s++) {
        #pragma unroll
        for (int q = 0; q < 5; q++) red[3 + s * 5 + q][threadIdx.x] = ps[s][q];
    }
    __syncthreads();
    for (int off = 128; off > 0; off >>= 1) {
        if (threadIdx.x < off) {
            #pragma unroll
            for (int r = 0; r < 18; r++)
                red[r][threadIdx.x] += red[r][threadIdx.x + off];
        }
        __syncthreads();
    }
    if (threadIdx.x == 0) {
        const float ncell[3] = {(float)N0, (float)N1, (float)N2};
        float coord = 0.f, conf = 0.f, cls = 0.f;
        #pragma unroll
        for (int s = 0; s < 3; s++) {
            float noobjTot = red[s][0];
            float co    = red[3 + s * 5 + 0][0];
            float ob    = red[3 + s * 5 + 1][0];
            float noadj = red[3 + s * 5 + 2][0];
            float cl    = red[3 + s * 5 + 3][0];
            float npos  = red[3 + s * 5 + 4][0];
            float nneg = ncell[s] - npos;
            float dn = fmaxf(npos, 1.f);
            conf += ob / dn + 0.5f * (noobjTot - noadj) / fmaxf(nneg, 1.f);
            if (npos > 0.f) {
                coord += co / dn;
                cls   += cl / fmaxf(npos * (float)NCLS, 1.f);
            }
        }
        out[0] = 5.0f * coord + conf + 1.0f * cls;
        out[1] = coord;
        out[2] = conf;
        out[3] = cls;
    }
}

extern "C" void kernel_launch(void* const* d_in, const int* in_sizes, int n_in,
                              void* d_out, int out_size, void* d_ws, size_t ws_size,
                              hipStream_t stream) {
    const float* p0 = (const float*)d_in[0];
    const float* p1 = (const float*)d_in[1];
    const float* p2 = (const float*)d_in[2];
    const float* tg = (const float*)d_in[3];
    float* out = (float*)d_out;

    char* ws = (char*)d_ws;
    float* noobj_part = (float*)ws;              // NOBT floats (2848 B)
    float* pos_part   = (float*)(ws + 4096);     // NPOS_BLOCKS*5 floats (12 KB)

    k_main<<<NBLK, 256, 0, stream>>>(p0, p1, p2, tg, noobj_part, pos_part);
    k_final<<<1, 256, 0, stream>>>(noobj_part, pos_part, out);
}